// Round 8
// baseline (16470.749 us; speedup 1.0000x reference)
//
#include <hip/hip_runtime.h>
#include <hip/hip_fp16.h>

#define Tt 1024
#define Ii 256
#define Hh 512
#define Cc 10
#define SPINMAX (1 << 24)

typedef _Float16 f16;
typedef _Float16 f16x8 __attribute__((ext_vector_type(8)));
typedef _Float16 f16x4 __attribute__((ext_vector_type(4)));
typedef _Float16 f16x2 __attribute__((ext_vector_type(2)));
typedef float    f32x4 __attribute__((ext_vector_type(4)));

// ---- ws byte offsets ----
#define OFF_WH1   4096u       // f16[512][512] w_hh1
#define OFF_WH2   528384u     // f16[512][512] w_hh2
#define OFF_XWR   1052672u    // f16 [16][8][8192] frag-major (2MB)
#define OFF_H1R   3149824u    // f16 [16][8][8192] row-major packed (2MB)
#define OFF_PAR   5246976u    // f16 [16][8][8192] frag-major (2MB)

// ---- flag int indices ----
#define FI_H1 0      // [8]     value p: h1 stores of steps <= p-1 certified; xw_p consumed
#define FI_H2 16     // [8]     value v: H2 completed step v-1 (par_{v-1} consumed)
#define FI_XW 128    // [8][3][2] value t+1: xw_t certified
#define FI_2A 256    // [8][3][4] value v: par_v certified; h1_{v+2} read

static __device__ __forceinline__ f32x4 mfma16(f16x8 a, f16x8 b, f32x4 c) {
  return __builtin_amdgcn_mfma_f32_16x16x32_f16(a, b, c, 0, 0, 0);
}
static __device__ __forceinline__ float fast_tanh(float v) {
  float e = __expf(2.0f * v);
  return 1.0f - 2.0f / (e + 1.0f);
}
static __device__ __forceinline__ int ldflag(const int* p) {
  return __hip_atomic_load(p, __ATOMIC_RELAXED, __HIP_MEMORY_SCOPE_AGENT);
}
static __device__ __forceinline__ void stflag(int* p, int v) {
  __hip_atomic_store(p, v, __ATOMIC_RELAXED, __HIP_MEMORY_SCOPE_AGENT);
}
static __device__ __forceinline__ f16x4 ld64cc(const f16* p) {
  union { unsigned long long u; f16x4 v; } U;
  U.u = __hip_atomic_load((const unsigned long long*)p, __ATOMIC_RELAXED, __HIP_MEMORY_SCOPE_AGENT);
  return U.v;
}
static __device__ __forceinline__ void st64cc(f16* p, f16x4 v) {
  union { unsigned long long u; f16x4 v; } U; U.v = v;
  __hip_atomic_store((unsigned long long*)p, U.u, __ATOMIC_RELAXED, __HIP_MEMORY_SCOPE_AGENT);
}
static __device__ __forceinline__ f16x8 ld128cc(const f16* p) {
  union { unsigned long long u[2]; f16x8 v; } U;
  U.u[0] = __hip_atomic_load((const unsigned long long*)p,     __ATOMIC_RELAXED, __HIP_MEMORY_SCOPE_AGENT);
  U.u[1] = __hip_atomic_load((const unsigned long long*)p + 1, __ATOMIC_RELAXED, __HIP_MEMORY_SCOPE_AGENT);
  return U.v;
}
static __device__ __forceinline__ void stu32cc(unsigned* p, unsigned v) {
  __hip_atomic_store(p, v, __ATOMIC_RELAXED, __HIP_MEMORY_SCOPE_AGENT);
}
static __device__ __forceinline__ int imin(int a, int b) { return a < b ? a : b; }

#define VMFENCE() asm volatile("s_waitcnt vmcnt(0)" ::: "memory")
#define LBAR() do { asm volatile("s_waitcnt lgkmcnt(0)" ::: "memory"); \
                    __builtin_amdgcn_s_barrier(); \
                    __builtin_amdgcn_sched_barrier(0); } while (0)

// ---------- prologue: w_hh1/w_hh2 fp32 -> f16 row-major ----------
__global__ void prep_weights(const float* __restrict__ w_hh1,
                             const float* __restrict__ w_hh2,
                             char* __restrict__ ws) {
  f16* wh1 = (f16*)(ws + OFF_WH1);
  f16* wh2 = (f16*)(ws + OFF_WH2);
  int i = blockIdx.x * 512 + threadIdx.x;
  if (i < 512 * 512) { wh1[i] = (f16)w_hh1[i]; wh2[i] = (f16)w_hh2[i]; }
}

// ---------- main persistent kernel ----------
__global__ __launch_bounds__(512, 1) void rnn_main(
    const float* __restrict__ x,
    const float* __restrict__ w_ih1, const float* __restrict__ w_ih2,
    const float* __restrict__ b_ih1, const float* __restrict__ b_hh1,
    const float* __restrict__ b_ih2, const float* __restrict__ b_hh2,
    const float* __restrict__ w_out, const float* __restrict__ b_out,
    float* __restrict__ out, char* __restrict__ ws)
{
  __shared__ __align__(16) char LS[147712];

  int* FL = (int*)ws;
  const f16* wh1f = (const f16*)(ws + OFF_WH1);
  const f16* wh2f = (const f16*)(ws + OFF_WH2);
  f16* xwr  = (f16*)(ws + OFF_XWR);
  f16* h1r  = (f16*)(ws + OFF_H1R);
  f16* parr = (f16*)(ws + OFF_PAR);

  const int bid  = blockIdx.x;
  const int tid  = threadIdx.x;
  const int wid  = tid >> 6;
  const int lane = tid & 63;
  const int lm   = lane & 15;
  const int lgrp = lane >> 4;
  const int lk8  = lgrp * 8;
  const int rlo  = (lane & 1) * 2;

  if (bid < 16) {
    // ============ H1 (0..7) / H2 (8..15): full-width recurrence, state in LDS ============
    const bool isH1 = (bid < 8);
    const int bg = bid & 7;
    f16* sB = (f16*)LS;                    // kc0..3 of whh, frag layout (128KB)
    f16* sH = (f16*)(LS + 131072);         // [16][520] state
    unsigned* sH32 = (unsigned*)sH;
    const f16* whh = isH1 ? wh1f : wh2f;
    const int wcol0 = wid * 64;

    for (int i = tid; i < 8192; i += 512) {
      const int kc = i >> 11, grp = (i >> 9) & 3, col = i & 511;
      *(f16x8*)&sB[(size_t)i * 8] =
        *(const f16x8*)&whh[(size_t)col * 512 + kc * 32 + grp * 8];
    }
    for (int i = tid; i < 16 * 260; i += 512) sH32[i] = 0u;
    __syncthreads();

    const int* pfxw = FL + FI_XW + bg * 6;
    const int* pf2a = FL + FI_2A + bg * 12;
    int dead = 0;
    bool have = true;
    f16x4 fvc[4], fvn[4];
    int cfeed, cg = 0;

    // prologue: feed for step 0
    if (isH1) {
      int v, sp = 0;
      do { v = imin(ldflag(pfxw + 0), ldflag(pfxw + 1));
           if (++sp > SPINMAX) { dead = 1; break; } } while (v < 1);
      const f16* fs = xwr + (size_t)bg * 8192;
      #pragma unroll
      for (int nt = 0; nt < 4; ++nt)
        fvc[nt] = ld64cc(fs + (wid * 4 + nt) * 256 + lm * 16 + lgrp * 4);
      cfeed = imin(ldflag(pfxw + 1 * 2), ldflag(pfxw + 1 * 2 + 1));   // set 1 pair
    } else {
      int v, sp = 0;
      do { v = imin(imin(ldflag(pf2a + 0), ldflag(pf2a + 1)),
                    imin(ldflag(pf2a + 2), ldflag(pf2a + 3)));
           if (++sp > SPINMAX) { dead = 1; break; } } while (v < 1);
      const f16* fs = parr + (size_t)bg * 8192;
      #pragma unroll
      for (int nt = 0; nt < 4; ++nt)
        fvc[nt] = ld64cc(fs + (wid * 4 + nt) * 256 + lm * 16 + lgrp * 4);
      cfeed = imin(imin(ldflag(pf2a + 4), ldflag(pf2a + 5)),
                   imin(ldflag(pf2a + 6), ldflag(pf2a + 7)));          // set 1 quad
    }

    for (int p = 0; p < Tt && !dead; ++p) {
      // ---- ensure current feed loaded (rare slow path) ----
      if (!have) {
        if (isH1) {
          const int s = p % 3; int v, sp = 0;
          do { v = imin(ldflag(pfxw + s * 2), ldflag(pfxw + s * 2 + 1));
               if (++sp > SPINMAX) { dead = 1; break; } } while (v < p + 1);
          const f16* fs = xwr + ((size_t)(p & 15) * 8 + bg) * 8192;
          #pragma unroll
          for (int nt = 0; nt < 4; ++nt)
            fvc[nt] = ld64cc(fs + (wid * 4 + nt) * 256 + lm * 16 + lgrp * 4);
        } else {
          const int sg = p % 3; int v, sp = 0;
          do { v = imin(imin(ldflag(pf2a + sg*4), ldflag(pf2a + sg*4+1)),
                        imin(ldflag(pf2a + sg*4+2), ldflag(pf2a + sg*4+3)));
               if (++sp > SPINMAX) { dead = 1; break; } } while (v < p + 1);
          const f16* fs = parr + ((size_t)(p & 15) * 8 + bg) * 8192;
          #pragma unroll
          for (int nt = 0; nt < 4; ++nt)
            fvc[nt] = ld64cc(fs + (wid * 4 + nt) * 256 + lm * 16 + lgrp * 4);
        }
      }
      // ---- H1 only: h1-ring overwrite guard (2A readers) ----
      if (isH1 && p >= 16 && cg < p - 15) {
        const int sg = (p - 16) % 3; int v, sp = 0;
        do { v = imin(imin(ldflag(pf2a + sg*4), ldflag(pf2a + sg*4+1)),
                      imin(ldflag(pf2a + sg*4+2), ldflag(pf2a + sg*4+3)));
             if (++sp > SPINMAX) { dead = 1; break; } } while (v < p - 15);
      }

      // ---- recurrent GEMM: A = h_{p-1} from LDS; B = sB(kc<4) + L2 stream ----
      f32x4 acc[4];
      #pragma unroll
      for (int nt = 0; nt < 4; ++nt) acc[nt] = f32x4{0.f, 0.f, 0.f, 0.f};
      if (p > 0) {
        #pragma unroll
        for (int kc = 0; kc < 16; ++kc) {
          f16x8 A = *(const f16x8*)&sH[lm * 520 + kc * 32 + lk8];
          if (kc < 4) {
            #pragma unroll
            for (int nt = 0; nt < 4; ++nt)
              acc[nt] = mfma16(A, *(const f16x8*)&sB[((size_t)(kc*4+lgrp)*512 + wcol0 + nt*16 + lm)*8], acc[nt]);
          } else {
            #pragma unroll
            for (int nt = 0; nt < 4; ++nt)
              acc[nt] = mfma16(A, *(const f16x8*)&whh[(size_t)(wcol0+nt*16+lm)*512 + kc*32 + lk8], acc[nt]);
          }
        }
      }
      LBAR();   // A: state reads complete

      #pragma unroll
      for (int nt = 0; nt < 4; ++nt)
        #pragma unroll
        for (int r = 0; r < 4; ++r) acc[nt][r] += (float)fvc[nt][r];

      // ---- publish progress (lag-1 certification; drain is of old stores only) ----
      if (isH1) {
        VMFENCE();
        if (tid == 0) stflag(FL + FI_H1 + bg, p);
      } else {
        if (tid == 0) stflag(FL + FI_H2 + bg, p + 1);   // par_p consumed; no drain needed
      }

      // ---- prefetch next feed (hidden a full step) ----
      have = false;
      if (p + 1 < Tt && cfeed >= p + 2) {
        const f16* fs = (isH1 ? xwr : parr) + ((size_t)((p + 1) & 15) * 8 + bg) * 8192;
        #pragma unroll
        for (int nt = 0; nt < 4; ++nt)
          fvn[nt] = ld64cc(fs + (wid * 4 + nt) * 256 + lm * 16 + lgrp * 4);
        have = true;
      }

      // ---- epilogue: tanh -> LDS state (+ h1 ring for H1) ----
      unsigned* ring32 = (unsigned*)(h1r + ((size_t)(p & 15) * 8 + bg) * 8192);
      #pragma unroll
      for (int nt = 0; nt < 4; ++nt) {
        const int cp = (wcol0 + nt * 16 + lm) >> 1;
        float v0 = fast_tanh(acc[nt][0]), v1 = fast_tanh(acc[nt][1]);
        float v2 = fast_tanh(acc[nt][2]), v3 = fast_tanh(acc[nt][3]);
        float o0 = __shfl_xor(v0,1,64), o1 = __shfl_xor(v1,1,64);
        float o2 = __shfl_xor(v2,1,64), o3 = __shfl_xor(v3,1,64);
        float m[4] = {v0,v1,v2,v3}, qd[4] = {o0,o1,o2,o3};
        #pragma unroll
        for (int r2 = 0; r2 < 2; ++r2) {
          const int rr = rlo + r2, row = lgrp * 4 + rr;
          float ve = (lane & 1) ? qd[rr] : m[rr];
          float vo = (lane & 1) ? m[rr] : qd[rr];
          union { f16x2 h; unsigned u; } P; P.h = f16x2{(f16)ve, (f16)vo};
          sH32[row * 260 + cp] = P.u;
          if (isH1) stu32cc(ring32 + row * 256 + cp, P.u);
        }
      }

      // ---- refresh caches for step p+1 (off critical path) ----
      if (isH1) {
        const int s2 = (p + 2) % 3;
        cfeed = imin(ldflag(pfxw + s2*2), ldflag(pfxw + s2*2 + 1));
        if (p + 1 >= 16) {
          const int sg = (p + 1 - 16) % 3;
          cg = imin(imin(ldflag(pf2a + sg*4), ldflag(pf2a + sg*4+1)),
                    imin(ldflag(pf2a + sg*4+2), ldflag(pf2a + sg*4+3)));
        }
      } else {
        const int sg2 = (p + 2) % 3;
        cfeed = imin(imin(ldflag(pf2a + sg2*4), ldflag(pf2a + sg2*4+1)),
                     imin(ldflag(pf2a + sg2*4+2), ldflag(pf2a + sg2*4+3)));
      }
      LBAR();   // B: state writes visible
      if (have) {
        #pragma unroll
        for (int nt = 0; nt < 4; ++nt) fvc[nt] = fvn[nt];
      }
    }

    VMFENCE();
    if (tid == 0) stflag(FL + (isH1 ? FI_H1 : FI_H2) + bg, Tt + 2);

    if (!isH1) {   // ---- final: out = h2_{T-1} @ w_out^T + b_out ----
      const int rl = wid * 2 + (lane >> 5);
      const int l32 = lane & 31;
      const f16* hr = &sH[rl * 520 + l32 * 16];
      f16x8 h0 = *(const f16x8*)hr;
      f16x8 h1v = *(const f16x8*)(hr + 8);
      float hf[16];
      #pragma unroll
      for (int j = 0; j < 8; ++j) { hf[j] = (float)h0[j]; hf[8 + j] = (float)h1v[j]; }
      #pragma unroll
      for (int c = 0; c < Cc; ++c) {
        const float* wr_ = w_out + (size_t)c * Hh + l32 * 16;
        float s = 0.f;
        #pragma unroll
        for (int j4 = 0; j4 < 4; ++j4) {
          float4 w4 = *(const float4*)(wr_ + j4 * 4);
          s += hf[j4*4]*w4.x + hf[j4*4+1]*w4.y + hf[j4*4+2]*w4.z + hf[j4*4+3]*w4.w;
        }
        #pragma unroll
        for (int off = 16; off >= 1; off >>= 1) s += __shfl_xor(s, off, 64);
        if (l32 == 0) out[(bg * 16 + rl) * Cc + c] = s + b_out[c];
      }
    }
  } else if (bid < 112) {
    // ============ 2A (16..111): par_q = h1_q @ w_ih2^T + b2, col-split x4, 3 sets ============
    const int idx = bid - 16;
    const int bg = idx / 12, r12 = idx % 12;
    const int set = r12 >> 2, cb = r12 & 3;
    f16* sW = (f16*)LS;                    // [16kc][4grp][128col][8] (128KB)
    f16* sA = (f16*)(LS + 131072);         // [16][520] staged h1

    for (int i = tid; i < 8192; i += 512) {
      const int kc = i >> 9, grp = (i >> 7) & 3, cl = i & 127;
      const float* sp = w_ih2 + (size_t)(cb * 128 + cl) * 512 + kc * 32 + grp * 8;
      float4 a = *(const float4*)sp, b = *(const float4*)(sp + 4);
      *(f16x8*)&sW[(size_t)i * 8] =
        f16x8{(f16)a.x,(f16)a.y,(f16)a.z,(f16)a.w,(f16)b.x,(f16)b.y,(f16)b.z,(f16)b.w};
    }
    const int gcol = cb * 128 + wid * 16 + lm;
    const float bias2v = b_ih2[gcol] + b_hh2[gcol];
    __syncthreads();

    int* myf = FL + FI_2A + (bg * 3 + set) * 4 + cb;
    const int row_ = tid >> 5, c32 = tid & 31;
    int dead = 0;
    f16x8 R0, R1;
    {
      int v, sp = 0;
      do { v = ldflag(FL + FI_H1 + bg); if (++sp > SPINMAX) { dead = 1; break; } }
      while (v < set + 1);
      const f16* hs = h1r + ((size_t)(set & 15) * 8 + bg) * 8192;
      R0 = ld128cc(hs + (size_t)tid * 16);
      R1 = ld128cc(hs + (size_t)tid * 16 + 8);
    }
    int cfh1 = ldflag(FL + FI_H1 + bg);
    int cfh2 = ldflag(FL + FI_H2 + bg);

    for (int q = set; q < Tt && !dead; q += 3) {
      VMFENCE();                                  // R arrived; old par stores drained
      if (q >= 3 && tid == 0) stflag(myf, q - 2); // certify par_{q-3}
      *(f16x8*)&sA[row_ * 520 + c32 * 16]     = R0;
      *(f16x8*)&sA[row_ * 520 + c32 * 16 + 8] = R1;
      LBAR();
      f32x4 acc = {bias2v, bias2v, bias2v, bias2v};
      #pragma unroll
      for (int kc = 0; kc < 16; ++kc) {
        f16x8 A = *(const f16x8*)&sA[lm * 520 + kc * 32 + lk8];
        f16x8 B = *(const f16x8*)&sW[((size_t)(kc * 4 + lgrp) * 128 + wid * 16 + lm) * 8];
        acc = mfma16(A, B, acc);
      }
      st64cc(parr + ((size_t)(q & 15) * 8 + bg) * 8192 + (cb * 8 + wid) * 256 + lm * 16 + lgrp * 4,
             f16x4{(f16)acc[0], (f16)acc[1], (f16)acc[2], (f16)acc[3]});
      if (q + 3 < Tt) {
        if (cfh1 < q + 4) {
          int v, sp = 0;
          do { v = ldflag(FL + FI_H1 + bg); if (++sp > SPINMAX) { dead = 1; break; } }
          while (v < q + 4);
        }
        if (q + 3 >= 16 && cfh2 < q - 12) {
          int v, sp = 0;
          do { v = ldflag(FL + FI_H2 + bg); if (++sp > SPINMAX) { dead = 1; break; } }
          while (v < q - 12);
        }
        const f16* hs = h1r + ((size_t)((q + 3) & 15) * 8 + bg) * 8192;
        R0 = ld128cc(hs + (size_t)tid * 16);
        R1 = ld128cc(hs + (size_t)tid * 16 + 8);
      }
      cfh1 = ldflag(FL + FI_H1 + bg);
      cfh2 = ldflag(FL + FI_H2 + bg);
      __syncthreads();
    }
    VMFENCE();
    if (tid == 0) stflag(myf, Tt + 2);
  } else {
    // ============ XW (112..159): xw_t = x_t @ w_ih1^T + b1, 3 sets x 2 halves ============
    const int idx = bid - 112;
    const int bg = idx / 6, r6 = idx % 6;
    const int set = r6 >> 1, half = r6 & 1;
    f16* sW = (f16*)LS;                    // [8kc][4grp][256col][8] (128KB)

    for (int i = tid; i < 8192; i += 512) {
      const int kc = i >> 10, grp = (i >> 8) & 3, cl = i & 255;
      const float* sp = w_ih1 + (size_t)(half * 256 + cl) * 256 + kc * 32 + grp * 8;
      float4 a = *(const float4*)sp, b = *(const float4*)(sp + 4);
      *(f16x8*)&sW[(size_t)i * 8] =
        f16x8{(f16)a.x,(f16)a.y,(f16)a.z,(f16)a.w,(f16)b.x,(f16)b.y,(f16)b.z,(f16)b.w};
    }
    const int gc0 = half * 256 + wid * 32 + lm;
    const float b1v0 = b_ih1[gc0] + b_hh1[gc0];
    const float b1v1 = b_ih1[gc0 + 16] + b_hh1[gc0 + 16];
    __syncthreads();

    int* myf = FL + FI_XW + (bg * 3 + set) * 2 + half;
    int cfh1 = 0, dead = 0;
    for (int t = set; t < Tt && !dead; t += 3) {
      if (t >= 16 && cfh1 < t - 15) {
        int v, sp = 0;
        do { v = ldflag(FL + FI_H1 + bg); if (++sp > SPINMAX) { dead = 1; break; } }
        while (v < t - 15);
      }
      f32x4 acc0 = {b1v0, b1v0, b1v0, b1v0};
      f32x4 acc1 = {b1v1, b1v1, b1v1, b1v1};
      const float* xr = x + ((size_t)(bg * 16 + lm) * Tt + t) * Ii + lk8;
      #pragma unroll
      for (int kc = 0; kc < 8; ++kc) {
        float4 a = *(const float4*)(xr + kc * 32);
        float4 b = *(const float4*)(xr + kc * 32 + 4);
        f16x8 A{(f16)a.x,(f16)a.y,(f16)a.z,(f16)a.w,(f16)b.x,(f16)b.y,(f16)b.z,(f16)b.w};
        acc0 = mfma16(A, *(const f16x8*)&sW[((size_t)(kc*4+lgrp)*256 + wid*32 + lm)*8], acc0);
        acc1 = mfma16(A, *(const f16x8*)&sW[((size_t)(kc*4+lgrp)*256 + wid*32 + 16 + lm)*8], acc1);
      }
      f16* dst = xwr + ((size_t)(t & 15) * 8 + bg) * 8192;
      st64cc(dst + (half*16 + wid*2 + 0)*256 + lm*16 + lgrp*4,
             f16x4{(f16)acc0[0],(f16)acc0[1],(f16)acc0[2],(f16)acc0[3]});
      st64cc(dst + (half*16 + wid*2 + 1)*256 + lm*16 + lgrp*4,
             f16x4{(f16)acc1[0],(f16)acc1[1],(f16)acc1[2],(f16)acc1[3]});
      VMFENCE();
      if (tid == 0) stflag(myf, t + 1);
      cfh1 = ldflag(FL + FI_H1 + bg);
    }
    if (tid == 0) stflag(myf, Tt + 2);
  }
}

extern "C" void kernel_launch(void* const* d_in, const int* in_sizes, int n_in,
                              void* d_out, int out_size, void* d_ws, size_t ws_size,
                              hipStream_t stream) {
  (void)in_sizes; (void)n_in; (void)out_size; (void)ws_size;
  const float* x     = (const float*)d_in[0];
  const float* w_ih1 = (const float*)d_in[1];
  const float* w_hh1 = (const float*)d_in[2];
  const float* b_ih1 = (const float*)d_in[3];
  const float* b_hh1 = (const float*)d_in[4];
  const float* w_ih2 = (const float*)d_in[5];
  const float* w_hh2 = (const float*)d_in[6];
  const float* b_ih2 = (const float*)d_in[7];
  const float* b_hh2 = (const float*)d_in[8];
  const float* w_out = (const float*)d_in[9];
  const float* b_out = (const float*)d_in[10];
  float* out = (float*)d_out;
  char* ws = (char*)d_ws;

  hipMemsetAsync(ws, 0, 4096, stream);   // flags
  hipLaunchKernelGGL(prep_weights, dim3(512), dim3(512), 0, stream, w_hh1, w_hh2, ws);
  hipLaunchKernelGGL(rnn_main, dim3(160), dim3(512), 0, stream,
                     x, w_ih1, w_ih2, b_ih1, b_hh1, b_ih2, b_hh2,
                     w_out, b_out, out, ws);
}

// Round 9
// 9623.080 us; speedup vs baseline: 1.7116x; 1.7116x over previous
//
#include <hip/hip_runtime.h>
#include <hip/hip_fp16.h>

#define Tt 1024
#define Ii 256
#define Hh 512
#define Cc 10
#define SPINMAX (1 << 20)

typedef _Float16 f16;
typedef _Float16 f16x8 __attribute__((ext_vector_type(8)));
typedef _Float16 f16x4 __attribute__((ext_vector_type(4)));
typedef _Float16 f16x2 __attribute__((ext_vector_type(2)));
typedef float    f32x4 __attribute__((ext_vector_type(4)));

// ---- ws byte offsets ----
#define OFF_WH1   32768u      // f16[512][512] w_hh1
#define OFF_WH2   557056u     // f16[512][512] w_hh2
#define OFF_XWR   1081344u    // f16 [16][8][8192]  xw ring
#define OFF_H1R   3178496u    // f16 [16][8][8192]  h1 ring
#define OFF_PAR   5275648u    // f16 [16][8][8192]  par ring

// flag slots (each padded to 32 ints = 128B):
//  H1 prog: slot bg            (value p: steps <= p-1 done+stores drained)
//  H2 prog: slot 8+bg          (value p: steps <= p-1 done [loads consumed])
//  XW:      slot 16+bg*8+set*2+half   (value t+1: xw_t certified)
//  2A:      slot 80+bg*16+set*4+cb    (value q+1: par_q certified, h1_q read)
#define FLG(i) (FL + (size_t)(i) * 32)

static __device__ __forceinline__ f32x4 mfma16(f16x8 a, f16x8 b, f32x4 c) {
  return __builtin_amdgcn_mfma_f32_16x16x32_f16(a, b, c, 0, 0, 0);
}
static __device__ __forceinline__ float fast_tanh(float v) {
  float e = __expf(2.0f * v);
  return 1.0f - 2.0f / (e + 1.0f);
}
static __device__ __forceinline__ int ldflag(const int* p) {
  return __hip_atomic_load(p, __ATOMIC_RELAXED, __HIP_MEMORY_SCOPE_AGENT);
}
static __device__ __forceinline__ void stflag(int* p, int v) {
  __hip_atomic_store(p, v, __ATOMIC_RELAXED, __HIP_MEMORY_SCOPE_AGENT);
}
static __device__ __forceinline__ f16x4 ld64cc(const f16* p) {
  union { unsigned long long u; f16x4 v; } U;
  U.u = __hip_atomic_load((const unsigned long long*)p, __ATOMIC_RELAXED, __HIP_MEMORY_SCOPE_AGENT);
  return U.v;
}
static __device__ __forceinline__ void st64cc(f16* p, f16x4 v) {
  union { unsigned long long u; f16x4 v; } U; U.v = v;
  __hip_atomic_store((unsigned long long*)p, U.u, __ATOMIC_RELAXED, __HIP_MEMORY_SCOPE_AGENT);
}
static __device__ __forceinline__ f16x8 ld128cc(const f16* p) {
  union { unsigned long long u[2]; f16x8 v; } U;
  U.u[0] = __hip_atomic_load((const unsigned long long*)p,     __ATOMIC_RELAXED, __HIP_MEMORY_SCOPE_AGENT);
  U.u[1] = __hip_atomic_load((const unsigned long long*)p + 1, __ATOMIC_RELAXED, __HIP_MEMORY_SCOPE_AGENT);
  return U.v;
}
static __device__ __forceinline__ void stu32cc(unsigned* p, unsigned v) {
  __hip_atomic_store(p, v, __ATOMIC_RELAXED, __HIP_MEMORY_SCOPE_AGENT);
}
static __device__ __forceinline__ int imin(int a, int b) { return a < b ? a : b; }

#define VMFENCE() asm volatile("s_waitcnt vmcnt(0)" ::: "memory")
#define LBAR() do { asm volatile("s_waitcnt lgkmcnt(0)" ::: "memory"); \
                    __builtin_amdgcn_s_barrier(); \
                    __builtin_amdgcn_sched_barrier(0); } while (0)

// ---------- prologue: w_hh1/w_hh2 fp32 -> f16 row-major ----------
__global__ void prep_weights(const float* __restrict__ w_hh1,
                             const float* __restrict__ w_hh2,
                             char* __restrict__ ws) {
  f16* wh1 = (f16*)(ws + OFF_WH1);
  f16* wh2 = (f16*)(ws + OFF_WH2);
  int i = blockIdx.x * 512 + threadIdx.x;
  if (i < 512 * 512) { wh1[i] = (f16)w_hh1[i]; wh2[i] = (f16)w_hh2[i]; }
}

// ---- one recurrence step for H1/H2 (J = p&3, compile-time at call site) ----
#define H_STEP(P, J, FVC, FVN, RA, RG, HVC, HVN)                                  \
  {                                                                               \
    const int p_ = (P);                                                           \
    /* 1. feed for this step (slow path only if prefetch missed) */               \
    if (!(HVC) && !dead) {                                                        \
      int v_ = 0;                                                                 \
      if (isH1) {                                                                 \
        const int* f0 = FLG(16 + bg * 8 + (J) * 2);                               \
        int sp_ = 0;                                                              \
        do { v_ = imin(ldflag(f0), ldflag(f0 + 32));                              \
             if (v_ >= p_ + 1) break;                                             \
             __builtin_amdgcn_s_sleep(4);                                         \
        } while (++sp_ < SPINMAX);                                                \
      } else {                                                                    \
        const int* f0 = FLG(80 + bg * 16 + (J) * 4);                              \
        int sp_ = 0;                                                              \
        do { v_ = imin(imin(ldflag(f0), ldflag(f0 + 32)),                         \
                       imin(ldflag(f0 + 64), ldflag(f0 + 96)));                   \
             if (v_ >= p_ + 1) break;                                             \
             __builtin_amdgcn_s_sleep(4);                                         \
        } while (++sp_ < SPINMAX);                                                \
      }                                                                           \
      if (v_ < p_ + 1) dead = 1;                                                  \
      const f16* fs_ = fring + ((size_t)(p_ & 15) * 8 + bg) * 8192;               \
      FVC[0] = ld64cc(fs_ + (wid * 4 + 0) * 256 + lm * 16 + lgrp * 4);            \
      FVC[1] = ld64cc(fs_ + (wid * 4 + 1) * 256 + lm * 16 + lgrp * 4);            \
      FVC[2] = ld64cc(fs_ + (wid * 4 + 2) * 256 + lm * 16 + lgrp * 4);            \
      FVC[3] = ld64cc(fs_ + (wid * 4 + 3) * 256 + lm * 16 + lgrp * 4);            \
    }                                                                             \
    /* 2. H1 ring-overwrite guard (slot p&15 held h1_{p-16}; set (p-16)&3==J) */  \
    if (isH1 && p_ >= 16 && !dead) {                                              \
      int cg_ = imin(imin(RA##_g[0], RA##_g[1]), imin(RA##_g[2], RA##_g[3]));     \
      (void)RG;                                                                   \
      if (cg_ < p_ - 15) {                                                        \
        const int* g0 = FLG(80 + bg * 16 + (J) * 4);                              \
        int sp_ = 0, v_ = 0;                                                      \
        do { v_ = imin(imin(ldflag(g0), ldflag(g0 + 32)),                         \
                       imin(ldflag(g0 + 64), ldflag(g0 + 96)));                   \
             if (v_ >= p_ - 15) break;                                            \
             __builtin_amdgcn_s_sleep(4);                                         \
        } while (++sp_ < SPINMAX);                                                \
        if (v_ < p_ - 15) dead = 1;                                               \
      }                                                                           \
    }                                                                             \
    /* 3. recurrent GEMM over h_{p-1} (LDS state) */                              \
    f32x4 acc[4];                                                                 \
    acc[0] = f32x4{0.f, 0.f, 0.f, 0.f};                                           \
    acc[1] = acc[0]; acc[2] = acc[0]; acc[3] = acc[0];                            \
    if (p_ > 0) {                                                                 \
      _Pragma("unroll")                                                           \
      for (int kc = 0; kc < 16; ++kc) {                                           \
        f16x8 A_ = *(const f16x8*)&sH[lm * 520 + kc * 32 + lk8];                  \
        if (kc < 4) {                                                             \
          _Pragma("unroll")                                                       \
          for (int nt = 0; nt < 4; ++nt)                                          \
            acc[nt] = mfma16(A_, *(const f16x8*)&sB[((size_t)(kc * 4 + lgrp) * 512 + wcol0 + nt * 16 + lm) * 8], acc[nt]); \
        } else {                                                                  \
          _Pragma("unroll")                                                       \
          for (int nt = 0; nt < 4; ++nt)                                          \
            acc[nt] = mfma16(A_, wb[kc - 4][nt], acc[nt]);                        \
        }                                                                         \
      }                                                                           \
    }                                                                             \
    LBAR(); /* state reads done before overwrite */                               \
    /* 4. publish every 2 steps (only old vmem outstanding here) */               \
    if ((p_ & 1) == 0 && p_ > 0) {                                                \
      if (isH1) { VMFENCE(); }                                                    \
      if (tid == 0) stflag(progF, p_);                                            \
    }                                                                             \
    /* 5. add feed (waitcnt: issued 2 steps ago -> hidden) */                     \
    _Pragma("unroll")                                                             \
    for (int nt = 0; nt < 4; ++nt) {                                              \
      acc[nt][0] += (float)FVC[nt][0]; acc[nt][1] += (float)FVC[nt][1];           \
      acc[nt][2] += (float)FVC[nt][2]; acc[nt][3] += (float)FVC[nt][3];           \
    }                                                                             \
    /* 6. prefetch feed p+2 (flag raws issued at p-2, eval here: hidden) */       \
    HVN = 0;                                                                      \
    if (p_ + 2 < Tt && !dead) {                                                   \
      int ca_ = isH1 ? imin(RA[0], RA[1])                                         \
                     : imin(imin(RA[0], RA[1]), imin(RA[2], RA[3]));              \
      if (ca_ >= p_ + 3) {                                                        \
        const f16* fs_ = fring + ((size_t)((p_ + 2) & 15) * 8 + bg) * 8192;       \
        FVN[0] = ld64cc(fs_ + (wid * 4 + 0) * 256 + lm * 16 + lgrp * 4);          \
        FVN[1] = ld64cc(fs_ + (wid * 4 + 1) * 256 + lm * 16 + lgrp * 4);          \
        FVN[2] = ld64cc(fs_ + (wid * 4 + 2) * 256 + lm * 16 + lgrp * 4);          \
        FVN[3] = ld64cc(fs_ + (wid * 4 + 3) * 256 + lm * 16 + lgrp * 4);          \
        HVN = 1;                                                                  \
      }                                                                           \
    }                                                                             \
    /* 7. epilogue: tanh -> LDS state (+ h1 ring for H1) */                       \
    unsigned* ring32_ = (unsigned*)(h1r + ((size_t)(p_ & 15) * 8 + bg) * 8192);   \
    _Pragma("unroll")                                                             \
    for (int nt = 0; nt < 4; ++nt) {                                              \
      const int cp_ = (wcol0 + nt * 16 + lm) >> 1;                                \
      float v0_ = fast_tanh(acc[nt][0]), v1_ = fast_tanh(acc[nt][1]);             \
      float v2_ = fast_tanh(acc[nt][2]), v3_ = fast_tanh(acc[nt][3]);             \
      float o0_ = __shfl_xor(v0_, 1, 64), o1_ = __shfl_xor(v1_, 1, 64);           \
      float o2_ = __shfl_xor(v2_, 1, 64), o3_ = __shfl_xor(v3_, 1, 64);           \
      float m_[4] = {v0_, v1_, v2_, v3_}, q_[4] = {o0_, o1_, o2_, o3_};           \
      _Pragma("unroll")                                                           \
      for (int r2 = 0; r2 < 2; ++r2) {                                            \
        const int rr_ = rlo + r2, row_ = lgrp * 4 + rr_;                          \
        float ve_ = (lane & 1) ? q_[rr_] : m_[rr_];                               \
        float vo_ = (lane & 1) ? m_[rr_] : q_[rr_];                               \
        union { f16x2 h; unsigned u; } P_; P_.h = f16x2{(f16)ve_, (f16)vo_};      \
        sH32[row_ * 260 + cp_] = P_.u;                                            \
        if (isH1) stu32cc(ring32_ + row_ * 256 + cp_, P_.u);                      \
      }                                                                           \
    }                                                                             \
    /* 8. issue flag raws for step p+2 (evaluated there: latency hidden) */       \
    if (isH1) {                                                                   \
      const int* f0 = FLG(16 + bg * 8 + (J) * 2);                                 \
      RA[0] = ldflag(f0); RA[1] = ldflag(f0 + 32);                                \
      const int* g0 = FLG(80 + bg * 16 + (((J) + 2) & 3) * 4);                    \
      RA##_g[0] = ldflag(g0);      RA##_g[1] = ldflag(g0 + 32);                   \
      RA##_g[2] = ldflag(g0 + 64); RA##_g[3] = ldflag(g0 + 96);                   \
    } else {                                                                      \
      const int* f0 = FLG(80 + bg * 16 + (J) * 4);                                \
      RA[0] = ldflag(f0);      RA[1] = ldflag(f0 + 32);                           \
      RA[2] = ldflag(f0 + 64); RA[3] = ldflag(f0 + 96);                           \
    }                                                                             \
    LBAR(); /* state writes visible for next step */                              \
  }

// ---------- main persistent kernel ----------
__global__ __launch_bounds__(512, 1) void rnn_main(
    const float* __restrict__ x,
    const float* __restrict__ w_ih1, const float* __restrict__ w_ih2,
    const float* __restrict__ b_ih1, const float* __restrict__ b_hh1,
    const float* __restrict__ b_ih2, const float* __restrict__ b_hh2,
    const float* __restrict__ w_out, const float* __restrict__ b_out,
    float* __restrict__ out, char* __restrict__ ws)
{
  __shared__ __align__(16) char LS[147712];

  int* FL = (int*)ws;
  const f16* wh1f = (const f16*)(ws + OFF_WH1);
  const f16* wh2f = (const f16*)(ws + OFF_WH2);
  f16* xwr  = (f16*)(ws + OFF_XWR);
  f16* h1r  = (f16*)(ws + OFF_H1R);
  f16* parr = (f16*)(ws + OFF_PAR);

  const int bid  = blockIdx.x;
  const int tid  = threadIdx.x;
  const int wid  = tid >> 6;
  const int lane = tid & 63;
  const int lm   = lane & 15;
  const int lgrp = lane >> 4;
  const int lk8  = lgrp * 8;
  const int rlo  = (lane & 1) * 2;

  if (bid < 16) {
    // ============ H1 (0..7) / H2 (8..15): full-width recurrence ============
    const bool isH1 = (bid < 8);
    const int bg = bid & 7;
    f16* sB = (f16*)LS;                    // kc0..3 of whh, frag layout (128KB)
    f16* sH = (f16*)(LS + 131072);         // [16][520] state
    unsigned* sH32 = (unsigned*)sH;
    const f16* whh = isH1 ? wh1f : wh2f;
    const f16* fring = isH1 ? xwr : parr;
    int* progF = FLG(isH1 ? bg : 8 + bg);
    const int wcol0 = wid * 64;

    for (int i = tid; i < 8192; i += 512) {
      const int kc = i >> 11, grp = (i >> 9) & 3, col = i & 511;
      *(f16x8*)&sB[(size_t)i * 8] =
        *(const f16x8*)&whh[(size_t)col * 512 + kc * 32 + grp * 8];
    }
    for (int i = tid; i < 16 * 260; i += 512) sH32[i] = 0u;
    f16x8 wb[12][4];
    #pragma unroll
    for (int kr = 0; kr < 12; ++kr)
      #pragma unroll
      for (int nt = 0; nt < 4; ++nt)
        wb[kr][nt] = *(const f16x8*)&whh[(size_t)(wcol0 + nt * 16 + lm) * 512 + (kr + 4) * 32 + lk8];
    __syncthreads();

    int dead = 0;
    f16x4 fv0[4], fv1[4], fv2[4], fv3[4];
    int rA0[4] = {0,0,0,0}, rA1[4] = {0,0,0,0};
    int rA0_g[4] = {0,0,0,0}, rA1_g[4] = {0,0,0,0};
    int hv0 = 1, hv1 = 1, hv2 = 0, hv3 = 0;

    // ---- prologue: block-load feeds 0 and 1; bootstrap raws ----
    {
      int v = 0, sp = 0;
      if (isH1) {
        const int* f0 = FLG(16 + bg * 8 + 0);
        do { v = imin(ldflag(f0), ldflag(f0 + 32)); if (v >= 1) break;
             __builtin_amdgcn_s_sleep(8); } while (++sp < SPINMAX);
      } else {
        const int* f0 = FLG(80 + bg * 16 + 0);
        do { v = imin(imin(ldflag(f0), ldflag(f0 + 32)),
                      imin(ldflag(f0 + 64), ldflag(f0 + 96)));
             if (v >= 1) break; __builtin_amdgcn_s_sleep(8); } while (++sp < SPINMAX);
      }
      if (v < 1) dead = 1;
      const f16* fs = fring + (size_t)bg * 8192;
      #pragma unroll
      for (int nt = 0; nt < 4; ++nt)
        fv0[nt] = ld64cc(fs + (wid * 4 + nt) * 256 + lm * 16 + lgrp * 4);
      v = 0; sp = 0;
      if (isH1) {
        const int* f0 = FLG(16 + bg * 8 + 1 * 2);
        do { v = imin(ldflag(f0), ldflag(f0 + 32)); if (v >= 2) break;
             __builtin_amdgcn_s_sleep(8); } while (++sp < SPINMAX);
      } else {
        const int* f0 = FLG(80 + bg * 16 + 1 * 4);
        do { v = imin(imin(ldflag(f0), ldflag(f0 + 32)),
                      imin(ldflag(f0 + 64), ldflag(f0 + 96)));
             if (v >= 2) break; __builtin_amdgcn_s_sleep(8); } while (++sp < SPINMAX);
      }
      if (v < 2) dead = 1;
      const f16* fs1 = fring + ((size_t)1 * 8 + bg) * 8192;
      #pragma unroll
      for (int nt = 0; nt < 4; ++nt)
        fv1[nt] = ld64cc(fs1 + (wid * 4 + nt) * 256 + lm * 16 + lgrp * 4);
      // bootstrap raws for decisions at steps 0 (set 2) and 1 (set 3)
      if (isH1) {
        const int* a0 = FLG(16 + bg * 8 + 2 * 2);
        rA0[0] = ldflag(a0); rA0[1] = ldflag(a0 + 32);
        const int* a1 = FLG(16 + bg * 8 + 3 * 2);
        rA1[0] = ldflag(a1); rA1[1] = ldflag(a1 + 32);
      } else {
        const int* a0 = FLG(80 + bg * 16 + 2 * 4);
        rA0[0] = ldflag(a0); rA0[1] = ldflag(a0 + 32);
        rA0[2] = ldflag(a0 + 64); rA0[3] = ldflag(a0 + 96);
        const int* a1 = FLG(80 + bg * 16 + 3 * 4);
        rA1[0] = ldflag(a1); rA1[1] = ldflag(a1 + 32);
        rA1[2] = ldflag(a1 + 64); rA1[3] = ldflag(a1 + 96);
      }
    }

    for (int pb = 0; pb < Tt; pb += 4) {
      if (dead) break;
      H_STEP(pb + 0, 0, fv0, fv2, rA0, rA0_g, hv0, hv2)
      H_STEP(pb + 1, 1, fv1, fv3, rA1, rA1_g, hv1, hv3)
      H_STEP(pb + 2, 2, fv2, fv0, rA0, rA0_g, hv2, hv0)
      H_STEP(pb + 3, 3, fv3, fv1, rA1, rA1_g, hv3, hv1)
    }

    VMFENCE();
    if (tid == 0) stflag(progF, Tt + 2);

    if (!isH1) {   // ---- final: out = h2_{T-1} @ w_out^T + b_out ----
      const int rl = wid * 2 + (lane >> 5);
      const int l32 = lane & 31;
      const f16* hr = &sH[rl * 520 + l32 * 16];
      f16x8 h0 = *(const f16x8*)hr;
      f16x8 h1v = *(const f16x8*)(hr + 8);
      float hf[16];
      #pragma unroll
      for (int j = 0; j < 8; ++j) { hf[j] = (float)h0[j]; hf[8 + j] = (float)h1v[j]; }
      #pragma unroll
      for (int c = 0; c < Cc; ++c) {
        const float* wr_ = w_out + (size_t)c * Hh + l32 * 16;
        float s = 0.f;
        #pragma unroll
        for (int j4 = 0; j4 < 4; ++j4) {
          float4 w4 = *(const float4*)(wr_ + j4 * 4);
          s += hf[j4*4]*w4.x + hf[j4*4+1]*w4.y + hf[j4*4+2]*w4.z + hf[j4*4+3]*w4.w;
        }
        #pragma unroll
        for (int off = 16; off >= 1; off >>= 1) s += __shfl_xor(s, off, 64);
        if (l32 == 0) out[(bg * 16 + rl) * Cc + c] = s + b_out[c];
      }
    }
  } else if (bid < 144) {
    // ============ 2A (16..143): par_q = h1_q @ w_ih2^T + b2 (4 sets x 4 cb) ============
    const int idx = bid - 16;
    const int bg = idx >> 4, r16 = idx & 15;
    const int set = r16 >> 2, cb = r16 & 3;
    f16* sW = (f16*)LS;                    // [16kc][4grp][128col][8] (128KB)
    f16* sA = (f16*)(LS + 131072);         // [16][520] staged h1

    for (int i = tid; i < 8192; i += 512) {
      const int kc = i >> 9, grp = (i >> 7) & 3, cl = i & 127;
      const float* sp = w_ih2 + (size_t)(cb * 128 + cl) * 512 + kc * 32 + grp * 8;
      float4 a = *(const float4*)sp, b = *(const float4*)(sp + 4);
      *(f16x8*)&sW[(size_t)i * 8] =
        f16x8{(f16)a.x,(f16)a.y,(f16)a.z,(f16)a.w,(f16)b.x,(f16)b.y,(f16)b.z,(f16)b.w};
    }
    const int gcol = cb * 128 + wid * 16 + lm;
    const float bias2v = b_ih2[gcol] + b_hh2[gcol];
    __syncthreads();

    int* myf = FLG(80 + bg * 16 + set * 4 + cb);
    const int* fH1 = FLG(bg);
    const int* fH2 = FLG(8 + bg);
    const int row_ = tid >> 5, c32 = tid & 31;
    int dead = 0;
    f16x8 R0, R1;
    {
      int v = 0, sp = 0;
      do { v = ldflag(fH1); if (v >= set + 1) break;
           __builtin_amdgcn_s_sleep(8); } while (++sp < SPINMAX);
      if (v < set + 1) dead = 1;
      const f16* hs = h1r + ((size_t)(set & 15) * 8 + bg) * 8192;
      R0 = ld128cc(hs + (size_t)tid * 16);
      R1 = ld128cc(hs + (size_t)tid * 16 + 8);
    }
    int rH1 = ldflag(fH1), rH2 = ldflag(fH2);

    for (int q = set; q < Tt && !dead; q += 4) {
      VMFENCE();                                // R arrived; old par stores drained
      *(f16x8*)&sA[row_ * 520 + c32 * 16]     = R0;
      *(f16x8*)&sA[row_ * 520 + c32 * 16 + 8] = R1;
      __syncthreads();
      f32x4 acc = {bias2v, bias2v, bias2v, bias2v};
      #pragma unroll
      for (int kc = 0; kc < 16; ++kc) {
        f16x8 A = *(const f16x8*)&sA[lm * 520 + kc * 32 + lk8];
        f16x8 B = *(const f16x8*)&sW[((size_t)(kc * 4 + lgrp) * 128 + wid * 16 + lm) * 8];
        acc = mfma16(A, B, acc);
      }
      st64cc(parr + ((size_t)(q & 15) * 8 + bg) * 8192 + (cb * 8 + wid) * 256 + lm * 16 + lgrp * 4,
             f16x4{(f16)acc[0], (f16)acc[1], (f16)acc[2], (f16)acc[3]});
      VMFENCE();
      if (tid == 0) stflag(myf, q + 1);          // certify par_q
      const int nq = q + 4;
      if (nq < Tt) {
        int haveR = 0;
        if (rH1 >= nq + 1) {                     // raw from last iter: hidden
          const f16* hs = h1r + ((size_t)(nq & 15) * 8 + bg) * 8192;
          R0 = ld128cc(hs + (size_t)tid * 16);
          R1 = ld128cc(hs + (size_t)tid * 16 + 8);
          haveR = 1;
        }
        if (nq >= 16 && rH2 < nq - 15) {         // par-ring overwrite guard
          int v = 0, sp = 0;
          do { v = ldflag(fH2); if (v >= nq - 15) break;
               __builtin_amdgcn_s_sleep(4); } while (++sp < SPINMAX);
          if (v < nq - 15) dead = 1;
        }
        if (!haveR && !dead) {
          int v = 0, sp = 0;
          do { v = ldflag(fH1); if (v >= nq + 1) break;
               __builtin_amdgcn_s_sleep(4); } while (++sp < SPINMAX);
          if (v < nq + 1) dead = 1;
          const f16* hs = h1r + ((size_t)(nq & 15) * 8 + bg) * 8192;
          R0 = ld128cc(hs + (size_t)tid * 16);
          R1 = ld128cc(hs + (size_t)tid * 16 + 8);
        }
      }
      rH1 = ldflag(fH1); rH2 = ldflag(fH2);
      __syncthreads();
    }
    VMFENCE();
    if (tid == 0) stflag(myf, Tt + 2);
  } else {
    // ============ XW (144..207): xw_t = x_t @ w_ih1^T + b1 (4 sets x 2 halves) ============
    const int idx = bid - 144;
    const int bg = idx >> 3, r8 = idx & 7;
    const int set = r8 >> 1, half = r8 & 1;
    f16* sW = (f16*)LS;                    // [8kc][4grp][256col][8] (128KB)

    for (int i = tid; i < 8192; i += 512) {
      const int kc = i >> 10, grp = (i >> 8) & 3, cl = i & 255;
      const float* sp = w_ih1 + (size_t)(half * 256 + cl) * 256 + kc * 32 + grp * 8;
      float4 a = *(const float4*)sp, b = *(const float4*)(sp + 4);
      *(f16x8*)&sW[(size_t)i * 8] =
        f16x8{(f16)a.x,(f16)a.y,(f16)a.z,(f16)a.w,(f16)b.x,(f16)b.y,(f16)b.z,(f16)b.w};
    }
    const int gc0 = half * 256 + wid * 32 + lm;
    const float b1v0 = b_ih1[gc0] + b_hh1[gc0];
    const float b1v1 = b_ih1[gc0 + 16] + b_hh1[gc0 + 16];
    __syncthreads();

    int* myf = FLG(16 + bg * 8 + set * 2 + half);
    const int* fH1 = FLG(bg);
    int rH1 = 0, dead = 0;
    for (int t = set; t < Tt && !dead; t += 4) {
      if (t >= 16 && rH1 < t - 15) {
        int v = 0, sp = 0;
        do { v = ldflag(fH1); if (v >= t - 15) break;
             __builtin_amdgcn_s_sleep(4); } while (++sp < SPINMAX);
        if (v < t - 15) dead = 1;
      }
      f32x4 acc0 = {b1v0, b1v0, b1v0, b1v0};
      f32x4 acc1 = {b1v1, b1v1, b1v1, b1v1};
      const float* xr = x + ((size_t)(bg * 16 + lm) * Tt + t) * Ii + lk8;
      #pragma unroll
      for (int kc = 0; kc < 8; ++kc) {
        float4 a = *(const float4*)(xr + kc * 32);
        float4 b = *(const float4*)(xr + kc * 32 + 4);
        f16x8 A{(f16)a.x,(f16)a.y,(f16)a.z,(f16)a.w,(f16)b.x,(f16)b.y,(f16)b.z,(f16)b.w};
        acc0 = mfma16(A, *(const f16x8*)&sW[((size_t)(kc*4+lgrp)*256 + wid*32 + lm)*8], acc0);
        acc1 = mfma16(A, *(const f16x8*)&sW[((size_t)(kc*4+lgrp)*256 + wid*32 + 16 + lm)*8], acc1);
      }
      f16* dst = xwr + ((size_t)(t & 15) * 8 + bg) * 8192;
      st64cc(dst + (half*16 + wid*2 + 0)*256 + lm*16 + lgrp*4,
             f16x4{(f16)acc0[0],(f16)acc0[1],(f16)acc0[2],(f16)acc0[3]});
      st64cc(dst + (half*16 + wid*2 + 1)*256 + lm*16 + lgrp*4,
             f16x4{(f16)acc1[0],(f16)acc1[1],(f16)acc1[2],(f16)acc1[3]});
      VMFENCE();
      if (tid == 0) stflag(myf, t + 1);
      rH1 = ldflag(fH1);                        // eval next iter: hidden
    }
    if (tid == 0) stflag(myf, Tt + 2);
  }
}

extern "C" void kernel_launch(void* const* d_in, const int* in_sizes, int n_in,
                              void* d_out, int out_size, void* d_ws, size_t ws_size,
                              hipStream_t stream) {
  (void)in_sizes; (void)n_in; (void)out_size; (void)ws_size;
  const float* x     = (const float*)d_in[0];
  const float* w_ih1 = (const float*)d_in[1];
  const float* w_hh1 = (const float*)d_in[2];
  const float* b_ih1 = (const float*)d_in[3];
  const float* b_hh1 = (const float*)d_in[4];
  const float* w_ih2 = (const float*)d_in[5];
  const float* w_hh2 = (const float*)d_in[6];
  const float* b_ih2 = (const float*)d_in[7];
  const float* b_hh2 = (const float*)d_in[8];
  const float* w_out = (const float*)d_in[9];
  const float* b_out = (const float*)d_in[10];
  float* out = (float*)d_out;
  char* ws = (char*)d_ws;

  hipMemsetAsync(ws, 0, 32768, stream);   // padded flags
  hipLaunchKernelGGL(prep_weights, dim3(512), dim3(512), 0, stream, w_hh1, w_hh2, ws);
  hipLaunchKernelGGL(rnn_main, dim3(208), dim3(512), 0, stream,
                     x, w_ih1, w_ih2, b_ih1, b_hh1, b_ih2, b_hh2,
                     w_out, b_out, out, ws);
}

// Round 10
// 8190.086 us; speedup vs baseline: 2.0111x; 1.1750x over previous
//
#include <hip/hip_runtime.h>
#include <hip/hip_fp16.h>

#define Tt 1024
#define Ii 256
#define Hh 512
#define Cc 10
#define SPINMAX (1 << 20)

typedef _Float16 f16;
typedef _Float16 f16x8 __attribute__((ext_vector_type(8)));
typedef _Float16 f16x4 __attribute__((ext_vector_type(4)));
typedef _Float16 f16x2 __attribute__((ext_vector_type(2)));
typedef float    f32x4 __attribute__((ext_vector_type(4)));

// ---- ws byte offsets ----
#define OFF_WH1   32768u
#define OFF_WH2   557056u
#define OFF_XWR   1081344u    // f16 [16][8][8192]  xw ring
#define OFF_H1R   3178496u    // f16 [16][8][8192]  h1 ring
#define OFF_PAR   5275648u    // f16 [16][8][8192]  par ring

// flag slots (each padded to 32 ints = 128B):
#define FLG(i) (FL + (size_t)(i) * 32)

static __device__ __forceinline__ f32x4 mfma16(f16x8 a, f16x8 b, f32x4 c) {
  return __builtin_amdgcn_mfma_f32_16x16x32_f16(a, b, c, 0, 0, 0);
}
static __device__ __forceinline__ float fast_tanh(float v) {
  float e = __expf(2.0f * v);
  return 1.0f - 2.0f / (e + 1.0f);
}
static __device__ __forceinline__ int ldflag(const int* p) {
  return __hip_atomic_load(p, __ATOMIC_RELAXED, __HIP_MEMORY_SCOPE_AGENT);
}
static __device__ __forceinline__ void stflag(int* p, int v) {
  __hip_atomic_store(p, v, __ATOMIC_RELAXED, __HIP_MEMORY_SCOPE_AGENT);
}
static __device__ __forceinline__ f16x4 ld64cc(const f16* p) {
  union { unsigned long long u; f16x4 v; } U;
  U.u = __hip_atomic_load((const unsigned long long*)p, __ATOMIC_RELAXED, __HIP_MEMORY_SCOPE_AGENT);
  return U.v;
}
static __device__ __forceinline__ void st64cc(f16* p, f16x4 v) {
  union { unsigned long long u; f16x4 v; } U; U.v = v;
  __hip_atomic_store((unsigned long long*)p, U.u, __ATOMIC_RELAXED, __HIP_MEMORY_SCOPE_AGENT);
}
static __device__ __forceinline__ f16x8 ld128cc(const f16* p) {
  union { unsigned long long u[2]; f16x8 v; } U;
  U.u[0] = __hip_atomic_load((const unsigned long long*)p,     __ATOMIC_RELAXED, __HIP_MEMORY_SCOPE_AGENT);
  U.u[1] = __hip_atomic_load((const unsigned long long*)p + 1, __ATOMIC_RELAXED, __HIP_MEMORY_SCOPE_AGENT);
  return U.v;
}
static __device__ __forceinline__ void stu32cc(unsigned* p, unsigned v) {
  __hip_atomic_store(p, v, __ATOMIC_RELAXED, __HIP_MEMORY_SCOPE_AGENT);
}
static __device__ __forceinline__ int imin(int a, int b) { return a < b ? a : b; }

#define VMFENCE() asm volatile("s_waitcnt vmcnt(0)" ::: "memory")
#define LBAR() do { asm volatile("s_waitcnt lgkmcnt(0)" ::: "memory"); \
                    __builtin_amdgcn_s_barrier(); \
                    __builtin_amdgcn_sched_barrier(0); } while (0)

__global__ void prep_weights(const float* __restrict__ w_hh1,
                             const float* __restrict__ w_hh2,
                             char* __restrict__ ws) {
  f16* wh1 = (f16*)(ws + OFF_WH1);
  f16* wh2 = (f16*)(ws + OFF_WH2);
  int i = blockIdx.x * 512 + threadIdx.x;
  if (i < 512 * 512) { wh1[i] = (f16)w_hh1[i]; wh2[i] = (f16)w_hh2[i]; }
}

// ---- one recurrence step; FVC/HAVC = parity feed buffer (refilled for p+2) ----
#define BODY(P, FVC, HAVC)                                                        \
  if (!dead) {                                                                    \
    const int p_ = (P);                                                           \
    const int s0_ = p_ & 3;                                                       \
    /* h1-ring overwrite guard (H1 only), raw evaluated 1 step late */            \
    if (isH1 && p_ >= 16) {                                                       \
      int g_ = imin(imin(rGa, rGb), imin(rGc, rGd));                              \
      if (g_ < p_ - 15) {                                                         \
        const int* g0 = FLG(80 + bg * 16 + s0_ * 4);                              \
        int v_ = 0, sp_ = 0;                                                      \
        do { v_ = imin(imin(ldflag(g0), ldflag(g0 + 32)),                         \
                       imin(ldflag(g0 + 64), ldflag(g0 + 96)));                   \
             if (v_ >= p_ - 15) break; __builtin_amdgcn_s_sleep(2);               \
        } while (++sp_ < SPINMAX);                                                \
        if (v_ < p_ - 15) dead = 1;                                               \
      }                                                                           \
    }                                                                             \
    /* slow-path feed (prefetch missed) */                                        \
    if (!(HAVC) && !dead) {                                                       \
      int v_ = 0, sp_ = 0;                                                        \
      if (isH1) {                                                                 \
        const int* f0 = FLG(16 + bg * 8 + s0_ * 2);                               \
        do { v_ = imin(ldflag(f0), ldflag(f0 + 32)); if (v_ >= p_ + 1) break;     \
             __builtin_amdgcn_s_sleep(2); } while (++sp_ < SPINMAX);              \
      } else {                                                                    \
        const int* f0 = FLG(80 + bg * 16 + s0_ * 4);                              \
        do { v_ = imin(imin(ldflag(f0), ldflag(f0 + 32)),                         \
                       imin(ldflag(f0 + 64), ldflag(f0 + 96)));                   \
             if (v_ >= p_ + 1) break; __builtin_amdgcn_s_sleep(2);                \
        } while (++sp_ < SPINMAX);                                                \
      }                                                                           \
      if (v_ < p_ + 1) dead = 1;                                                  \
      const f16* fs_ = fring + ((size_t)(p_ & 15) * 8 + bg) * 8192;               \
      FVC[0] = ld64cc(fs_ + (wid * 4 + 0) * 256 + lm * 16 + lgrp * 4);            \
      FVC[1] = ld64cc(fs_ + (wid * 4 + 1) * 256 + lm * 16 + lgrp * 4);            \
      FVC[2] = ld64cc(fs_ + (wid * 4 + 2) * 256 + lm * 16 + lgrp * 4);            \
      FVC[3] = ld64cc(fs_ + (wid * 4 + 3) * 256 + lm * 16 + lgrp * 4);            \
    }                                                                             \
    /* MFMA: B = sB(kc0-3, LDS) + wbr(kc4-14, pinned VGPR) + kc15 (L1 stream) */  \
    f16x8 w15_[4];                                                                \
    if (p_ > 0) {                                                                 \
      _Pragma("unroll")                                                           \
      for (int nt = 0; nt < 4; ++nt)                                              \
        w15_[nt] = *(const f16x8*)&whh[(size_t)(wcol0 + nt * 16 + lm) * 512 + 15 * 32 + lk8]; \
    }                                                                             \
    f32x4 acc[4];                                                                 \
    acc[0] = f32x4{0.f, 0.f, 0.f, 0.f};                                           \
    acc[1] = acc[0]; acc[2] = acc[0]; acc[3] = acc[0];                            \
    if (p_ > 0) {                                                                 \
      _Pragma("unroll")                                                           \
      for (int kc = 0; kc < 16; ++kc) {                                           \
        f16x8 A_ = *(const f16x8*)&sH[lm * 520 + kc * 32 + lk8];                  \
        _Pragma("unroll")                                                         \
        for (int nt = 0; nt < 4; ++nt) {                                          \
          f16x8 B_;                                                               \
          if (kc < 4)       B_ = *(const f16x8*)&sB[((size_t)(kc * 4 + lgrp) * 512 + wcol0 + nt * 16 + lm) * 8]; \
          else if (kc < 15) B_ = wbr[kc - 4][nt];                                 \
          else              B_ = w15_[nt];                                        \
          acc[nt] = mfma16(A_, B_, acc[nt]);                                      \
        }                                                                         \
      }                                                                           \
    }                                                                             \
    LBAR(); /* state reads done */                                                \
    /* publish: H1 every 4 (fence sees only old ops), H2 every 2 fence-free */    \
    if (p_ > 0) {                                                                 \
      if (isH1) {                                                                 \
        if ((p_ & 3) == 0) { VMFENCE(); if (tid == 0) stflag(progF, p_); }        \
      } else {                                                                    \
        if ((p_ & 1) == 0 && tid == 0) stflag(progF, p_);                         \
      }                                                                           \
    }                                                                             \
    /* add feed */                                                                \
    _Pragma("unroll")                                                             \
    for (int nt = 0; nt < 4; ++nt) {                                              \
      acc[nt][0] += (float)FVC[nt][0]; acc[nt][1] += (float)FVC[nt][1];           \
      acc[nt][2] += (float)FVC[nt][2]; acc[nt][3] += (float)FVC[nt][3];           \
    }                                                                             \
    /* refill this parity buffer with feed p+2 (raws 1 step old) */               \
    HAVC = 0;                                                                     \
    if (p_ + 2 < Tt && !dead) {                                                   \
      int ca_ = isH1 ? imin(rFa, rFb) : imin(imin(rFa, rFb), imin(rFc, rFd));     \
      if (ca_ >= p_ + 3) {                                                        \
        const f16* fs_ = fring + ((size_t)((p_ + 2) & 15) * 8 + bg) * 8192;       \
        FVC[0] = ld64cc(fs_ + (wid * 4 + 0) * 256 + lm * 16 + lgrp * 4);          \
        FVC[1] = ld64cc(fs_ + (wid * 4 + 1) * 256 + lm * 16 + lgrp * 4);          \
        FVC[2] = ld64cc(fs_ + (wid * 4 + 2) * 256 + lm * 16 + lgrp * 4);          \
        FVC[3] = ld64cc(fs_ + (wid * 4 + 3) * 256 + lm * 16 + lgrp * 4);          \
        HAVC = 1;                                                                 \
      }                                                                           \
    }                                                                             \
    /* epilogue: tanh -> LDS state (+ h1 ring for H1) */                          \
    unsigned* ring32_ = (unsigned*)(h1r + ((size_t)(p_ & 15) * 8 + bg) * 8192);   \
    _Pragma("unroll")                                                             \
    for (int nt = 0; nt < 4; ++nt) {                                              \
      const int cp_ = (wcol0 + nt * 16 + lm) >> 1;                                \
      float v0_ = fast_tanh(acc[nt][0]), v1_ = fast_tanh(acc[nt][1]);             \
      float v2_ = fast_tanh(acc[nt][2]), v3_ = fast_tanh(acc[nt][3]);             \
      float o0_ = __shfl_xor(v0_, 1, 64), o1_ = __shfl_xor(v1_, 1, 64);           \
      float o2_ = __shfl_xor(v2_, 1, 64), o3_ = __shfl_xor(v3_, 1, 64);           \
      float m_[4] = {v0_, v1_, v2_, v3_}, q_[4] = {o0_, o1_, o2_, o3_};           \
      _Pragma("unroll")                                                           \
      for (int r2 = 0; r2 < 2; ++r2) {                                            \
        const int rr_ = rlo + r2, row_ = lgrp * 4 + rr_;                          \
        float ve_ = (lane & 1) ? q_[rr_] : m_[rr_];                               \
        float vo_ = (lane & 1) ? m_[rr_] : q_[rr_];                               \
        union { f16x2 h; unsigned u; } P_; P_.h = f16x2{(f16)ve_, (f16)vo_};      \
        sH32[row_ * 260 + cp_] = P_.u;                                            \
        if (isH1) stu32cc(ring32_ + row_ * 256 + cp_, P_.u);                      \
      }                                                                           \
    }                                                                             \
    /* issue raws for next step (evaluated there: latency hidden) */              \
    if (isH1) {                                                                   \
      const int* f0 = FLG(16 + bg * 8 + (((p_ + 3) & 3)) * 2);                    \
      rFa = ldflag(f0); rFb = ldflag(f0 + 32);                                    \
      const int* g0 = FLG(80 + bg * 16 + (((p_ + 1) & 3)) * 4);                   \
      rGa = ldflag(g0); rGb = ldflag(g0 + 32);                                    \
      rGc = ldflag(g0 + 64); rGd = ldflag(g0 + 96);                               \
    } else {                                                                      \
      const int* f0 = FLG(80 + bg * 16 + (((p_ + 3) & 3)) * 4);                   \
      rFa = ldflag(f0); rFb = ldflag(f0 + 32);                                    \
      rFc = ldflag(f0 + 64); rFd = ldflag(f0 + 96);                               \
    }                                                                             \
    LBAR(); /* state writes visible */                                            \
  }

__global__ __launch_bounds__(512) __attribute__((amdgpu_waves_per_eu(2, 2)))
void rnn_main(
    const float* __restrict__ x,
    const float* __restrict__ w_ih1, const float* __restrict__ w_ih2,
    const float* __restrict__ b_ih1, const float* __restrict__ b_hh1,
    const float* __restrict__ b_ih2, const float* __restrict__ b_hh2,
    const float* __restrict__ w_out, const float* __restrict__ b_out,
    float* __restrict__ out, char* __restrict__ ws)
{
  __shared__ __align__(16) char LS[147712];

  int* FL = (int*)ws;
  const f16* wh1f = (const f16*)(ws + OFF_WH1);
  const f16* wh2f = (const f16*)(ws + OFF_WH2);
  f16* xwr  = (f16*)(ws + OFF_XWR);
  f16* h1r  = (f16*)(ws + OFF_H1R);
  f16* parr = (f16*)(ws + OFF_PAR);

  const int bid  = blockIdx.x;
  const int tid  = threadIdx.x;
  const int wid  = tid >> 6;
  const int lane = tid & 63;
  const int lm   = lane & 15;
  const int lgrp = lane >> 4;
  const int lk8  = lgrp * 8;
  const int rlo  = (lane & 1) * 2;

  if (bid < 16) {
    // ============ H1 (0..7) / H2 (8..15) ============
    const bool isH1 = (bid < 8);
    const int bg = bid & 7;
    f16* sB = (f16*)LS;
    f16* sH = (f16*)(LS + 131072);
    unsigned* sH32 = (unsigned*)sH;
    const f16* whh = isH1 ? wh1f : wh2f;
    const f16* fring = isH1 ? xwr : parr;
    int* progF = FLG(isH1 ? bg : 8 + bg);
    const int wcol0 = wid * 64;

    for (int i = tid; i < 8192; i += 512) {
      const int kc = i >> 11, grp = (i >> 9) & 3, col = i & 511;
      *(f16x8*)&sB[(size_t)i * 8] =
        *(const f16x8*)&whh[(size_t)col * 512 + kc * 32 + grp * 8];
    }
    for (int i = tid; i < 16 * 260; i += 512) sH32[i] = 0u;
    // kc4..14 pinned in VGPRs (176/lane); asm makes them opaque -> no remat
    f16x8 wbr[11][4];
    #pragma unroll
    for (int kr = 0; kr < 11; ++kr) {
      #pragma unroll
      for (int nt = 0; nt < 4; ++nt) {
        wbr[kr][nt] = *(const f16x8*)&whh[(size_t)(wcol0 + nt * 16 + lm) * 512 + (kr + 4) * 32 + lk8];
        asm volatile("" : "+v"(wbr[kr][nt]));
      }
    }
    __syncthreads();

    int dead = 0;
    f16x4 fX[4], fY[4];
    int hX = 0, hY = 0;
    int rFa = 0, rFb = 0, rFc = 0, rFd = 0;
    int rGa = 0, rGb = 0, rGc = 0, rGd = 0;

    // prologue: feeds 0 (X) and 1 (Y); bootstrap feed raws for step 0 (set 2)
    {
      int v = 0, sp = 0;
      if (isH1) {
        const int* f0 = FLG(16 + bg * 8 + 0);
        do { v = imin(ldflag(f0), ldflag(f0 + 32)); if (v >= 1) break;
             __builtin_amdgcn_s_sleep(8); } while (++sp < SPINMAX);
      } else {
        const int* f0 = FLG(80 + bg * 16 + 0);
        do { v = imin(imin(ldflag(f0), ldflag(f0 + 32)),
                      imin(ldflag(f0 + 64), ldflag(f0 + 96)));
             if (v >= 1) break; __builtin_amdgcn_s_sleep(8); } while (++sp < SPINMAX);
      }
      if (v < 1) dead = 1;
      const f16* fs = fring + (size_t)bg * 8192;
      #pragma unroll
      for (int nt = 0; nt < 4; ++nt)
        fX[nt] = ld64cc(fs + (wid * 4 + nt) * 256 + lm * 16 + lgrp * 4);
      hX = 1;
      v = 0; sp = 0;
      if (isH1) {
        const int* f0 = FLG(16 + bg * 8 + 1 * 2);
        do { v = imin(ldflag(f0), ldflag(f0 + 32)); if (v >= 2) break;
             __builtin_amdgcn_s_sleep(8); } while (++sp < SPINMAX);
      } else {
        const int* f0 = FLG(80 + bg * 16 + 1 * 4);
        do { v = imin(imin(ldflag(f0), ldflag(f0 + 32)),
                      imin(ldflag(f0 + 64), ldflag(f0 + 96)));
             if (v >= 2) break; __builtin_amdgcn_s_sleep(8); } while (++sp < SPINMAX);
      }
      if (v < 2) dead = 1;
      const f16* fs1 = fring + ((size_t)1 * 8 + bg) * 8192;
      #pragma unroll
      for (int nt = 0; nt < 4; ++nt)
        fY[nt] = ld64cc(fs1 + (wid * 4 + nt) * 256 + lm * 16 + lgrp * 4);
      hY = 1;
      if (isH1) {
        const int* a0 = FLG(16 + bg * 8 + 2 * 2);
        rFa = ldflag(a0); rFb = ldflag(a0 + 32);
      } else {
        const int* a0 = FLG(80 + bg * 16 + 2 * 4);
        rFa = ldflag(a0); rFb = ldflag(a0 + 32);
        rFc = ldflag(a0 + 64); rFd = ldflag(a0 + 96);
      }
    }

    for (int p2 = 0; p2 < Tt; p2 += 2) {
      BODY(p2,     fX, hX)
      BODY(p2 + 1, fY, hY)
    }

    VMFENCE();
    if (tid == 0) stflag(progF, Tt + 2);

    if (!isH1) {   // ---- final: out = h2_{T-1} @ w_out^T + b_out ----
      const int rl = wid * 2 + (lane >> 5);
      const int l32 = lane & 31;
      const f16* hr = &sH[rl * 520 + l32 * 16];
      f16x8 h0 = *(const f16x8*)hr;
      f16x8 h1v = *(const f16x8*)(hr + 8);
      float hf[16];
      #pragma unroll
      for (int j = 0; j < 8; ++j) { hf[j] = (float)h0[j]; hf[8 + j] = (float)h1v[j]; }
      #pragma unroll
      for (int c = 0; c < Cc; ++c) {
        const float* wr_ = w_out + (size_t)c * Hh + l32 * 16;
        float s = 0.f;
        #pragma unroll
        for (int j4 = 0; j4 < 4; ++j4) {
          float4 w4 = *(const float4*)(wr_ + j4 * 4);
          s += hf[j4*4]*w4.x + hf[j4*4+1]*w4.y + hf[j4*4+2]*w4.z + hf[j4*4+3]*w4.w;
        }
        #pragma unroll
        for (int off = 16; off >= 1; off >>= 1) s += __shfl_xor(s, off, 64);
        if (l32 == 0) out[(bg * 16 + rl) * Cc + c] = s + b_out[c];
      }
    }
  } else if (bid < 144) {
    // ============ 2A (16..143): par_q = h1_q @ w_ih2^T + b2 (4 sets x 4 cb) ============
    const int idx = bid - 16;
    const int bg = idx >> 4, r16 = idx & 15;
    const int set = r16 >> 2, cb = r16 & 3;
    f16* sW = (f16*)LS;
    f16* sA = (f16*)(LS + 131072);

    for (int i = tid; i < 8192; i += 512) {
      const int kc = i >> 9, grp = (i >> 7) & 3, cl = i & 127;
      const float* sp = w_ih2 + (size_t)(cb * 128 + cl) * 512 + kc * 32 + grp * 8;
      float4 a = *(const float4*)sp, b = *(const float4*)(sp + 4);
      *(f16x8*)&sW[(size_t)i * 8] =
        f16x8{(f16)a.x,(f16)a.y,(f16)a.z,(f16)a.w,(f16)b.x,(f16)b.y,(f16)b.z,(f16)b.w};
    }
    const int gcol = cb * 128 + wid * 16 + lm;
    const float bias2v = b_ih2[gcol] + b_hh2[gcol];
    __syncthreads();

    int* myf = FLG(80 + bg * 16 + set * 4 + cb);
    const int* fH1 = FLG(bg);
    const int* fH2 = FLG(8 + bg);
    const int row_ = tid >> 5, c32 = tid & 31;
    int dead = 0;
    f16x8 R0, R1;
    {
      int v = 0, sp = 0;
      do { v = ldflag(fH1); if (v >= set + 1) break;
           __builtin_amdgcn_s_sleep(8); } while (++sp < SPINMAX);
      if (v < set + 1) dead = 1;
      const f16* hs = h1r + ((size_t)(set & 15) * 8 + bg) * 8192;
      R0 = ld128cc(hs + (size_t)tid * 16);
      R1 = ld128cc(hs + (size_t)tid * 16 + 8);
    }
    int rH1 = ldflag(fH1), rH2 = ldflag(fH2);

    for (int q = set; q < Tt && !dead; q += 4) {
      VMFENCE();
      *(f16x8*)&sA[row_ * 520 + c32 * 16]     = R0;
      *(f16x8*)&sA[row_ * 520 + c32 * 16 + 8] = R1;
      __syncthreads();
      f32x4 acc = {bias2v, bias2v, bias2v, bias2v};
      #pragma unroll
      for (int kc = 0; kc < 16; ++kc) {
        f16x8 A = *(const f16x8*)&sA[lm * 520 + kc * 32 + lk8];
        f16x8 B = *(const f16x8*)&sW[((size_t)(kc * 4 + lgrp) * 128 + wid * 16 + lm) * 8];
        acc = mfma16(A, B, acc);
      }
      st64cc(parr + ((size_t)(q & 15) * 8 + bg) * 8192 + (cb * 8 + wid) * 256 + lm * 16 + lgrp * 4,
             f16x4{(f16)acc[0], (f16)acc[1], (f16)acc[2], (f16)acc[3]});
      VMFENCE();
      if (tid == 0) stflag(myf, q + 1);
      const int nq = q + 4;
      if (nq < Tt) {
        int haveR = 0;
        if (rH1 >= nq + 1) {
          const f16* hs = h1r + ((size_t)(nq & 15) * 8 + bg) * 8192;
          R0 = ld128cc(hs + (size_t)tid * 16);
          R1 = ld128cc(hs + (size_t)tid * 16 + 8);
          haveR = 1;
        }
        if (nq >= 16 && rH2 < nq - 15) {
          int v = 0, sp = 0;
          do { v = ldflag(fH2); if (v >= nq - 15) break;
               __builtin_amdgcn_s_sleep(4); } while (++sp < SPINMAX);
          if (v < nq - 15) dead = 1;
        }
        if (!haveR && !dead) {
          int v = 0, sp = 0;
          do { v = ldflag(fH1); if (v >= nq + 1) break;
               __builtin_amdgcn_s_sleep(4); } while (++sp < SPINMAX);
          if (v < nq + 1) dead = 1;
          const f16* hs = h1r + ((size_t)(nq & 15) * 8 + bg) * 8192;
          R0 = ld128cc(hs + (size_t)tid * 16);
          R1 = ld128cc(hs + (size_t)tid * 16 + 8);
        }
      }
      rH1 = ldflag(fH1); rH2 = ldflag(fH2);
      __syncthreads();
    }
    VMFENCE();
    if (tid == 0) stflag(myf, Tt + 2);
  } else {
    // ============ XW (144..207): xw_t = x_t @ w_ih1^T + b1 (4 sets x 2 halves) ============
    const int idx = bid - 144;
    const int bg = idx >> 3, r8 = idx & 7;
    const int set = r8 >> 1, half = r8 & 1;
    f16* sW = (f16*)LS;

    for (int i = tid; i < 8192; i += 512) {
      const int kc = i >> 10, grp = (i >> 8) & 3, cl = i & 255;
      const float* sp = w_ih1 + (size_t)(half * 256 + cl) * 256 + kc * 32 + grp * 8;
      float4 a = *(const float4*)sp, b = *(const float4*)(sp + 4);
      *(f16x8*)&sW[(size_t)i * 8] =
        f16x8{(f16)a.x,(f16)a.y,(f16)a.z,(f16)a.w,(f16)b.x,(f16)b.y,(f16)b.z,(f16)b.w};
    }
    const int gc0 = half * 256 + wid * 32 + lm;
    const float b1v0 = b_ih1[gc0] + b_hh1[gc0];
    const float b1v1 = b_ih1[gc0 + 16] + b_hh1[gc0 + 16];
    __syncthreads();

    int* myf = FLG(16 + bg * 8 + set * 2 + half);
    const int* fH1 = FLG(bg);
    int rH1 = 0, dead = 0;
    for (int t = set; t < Tt && !dead; t += 4) {
      if (t >= 16 && rH1 < t - 15) {
        int v = 0, sp = 0;
        do { v = ldflag(fH1); if (v >= t - 15) break;
             __builtin_amdgcn_s_sleep(4); } while (++sp < SPINMAX);
        if (v < t - 15) dead = 1;
      }
      f32x4 acc0 = {b1v0, b1v0, b1v0, b1v0};
      f32x4 acc1 = {b1v1, b1v1, b1v1, b1v1};
      const float* xr = x + ((size_t)(bg * 16 + lm) * Tt + t) * Ii + lk8;
      #pragma unroll
      for (int kc = 0; kc < 8; ++kc) {
        float4 a = *(const float4*)(xr + kc * 32);
        float4 b = *(const float4*)(xr + kc * 32 + 4);
        f16x8 A{(f16)a.x,(f16)a.y,(f16)a.z,(f16)a.w,(f16)b.x,(f16)b.y,(f16)b.z,(f16)b.w};
        acc0 = mfma16(A, *(const f16x8*)&sW[((size_t)(kc*4+lgrp)*256 + wid*32 + lm)*8], acc0);
        acc1 = mfma16(A, *(const f16x8*)&sW[((size_t)(kc*4+lgrp)*256 + wid*32 + 16 + lm)*8], acc1);
      }
      f16* dst = xwr + ((size_t)(t & 15) * 8 + bg) * 8192;
      st64cc(dst + (half*16 + wid*2 + 0)*256 + lm*16 + lgrp*4,
             f16x4{(f16)acc0[0],(f16)acc0[1],(f16)acc0[2],(f16)acc0[3]});
      st64cc(dst + (half*16 + wid*2 + 1)*256 + lm*16 + lgrp*4,
             f16x4{(f16)acc1[0],(f16)acc1[1],(f16)acc1[2],(f16)acc1[3]});
      VMFENCE();
      if (tid == 0) stflag(myf, t + 1);
      rH1 = ldflag(fH1);
    }
    if (tid == 0) stflag(myf, Tt + 2);
  }
}

extern "C" void kernel_launch(void* const* d_in, const int* in_sizes, int n_in,
                              void* d_out, int out_size, void* d_ws, size_t ws_size,
                              hipStream_t stream) {
  (void)in_sizes; (void)n_in; (void)out_size; (void)ws_size;
  const float* x     = (const float*)d_in[0];
  const float* w_ih1 = (const float*)d_in[1];
  const float* w_hh1 = (const float*)d_in[2];
  const float* b_ih1 = (const float*)d_in[3];
  const float* b_hh1 = (const float*)d_in[4];
  const float* w_ih2 = (const float*)d_in[5];
  const float* w_hh2 = (const float*)d_in[6];
  const float* b_ih2 = (const float*)d_in[7];
  const float* b_hh2 = (const float*)d_in[8];
  const float* w_out = (const float*)d_in[9];
  const float* b_out = (const float*)d_in[10];
  float* out = (float*)d_out;
  char* ws = (char*)d_ws;

  hipMemsetAsync(ws, 0, 32768, stream);
  hipLaunchKernelGGL(prep_weights, dim3(512), dim3(512), 0, stream, w_hh1, w_hh2, ws);
  hipLaunchKernelGGL(rnn_main, dim3(208), dim3(512), 0, stream,
                     x, w_ih1, w_ih2, b_ih1, b_hh1, b_ih2, b_hh2,
                     w_out, b_out, out, ws);
}